// Round 8
// baseline (276.824 us; speedup 1.0000x reference)
//
#include <hip/hip_runtime.h>
#include <math.h>

// ---------------------------------------------------------------------------
// SingleHeadSelfAttention: B=4, S=2048, C=2048, d=512
// R14: ALL four GEMMs moved to a 128x128-tile, 4-wave (2x2), acc[4][4] ring
//      core with a 3-slot static-LDS ring (48 KB).
//      WHY: the 256^2 core's unified reg use (128 VGPR + 128 AGPR acc) = 256
//      per wave -> 2048-reg pool caps the CU at 8 waves = ONE 512-thread wg.
//      One barrier domain -> all waves read LDS together then MFMA together
//      (chunk = 1150 cy LDS + 1242 cy MFMA SUMMED, MfmaUtil stuck ~31%).
//      [This also explains R11 (forced 128-reg bound -> acc spill -> timeout)
//      and R12 (2nd 512-wg never resident: 16x256 regs > pool).]
//      The 128^2 core needs ~150 unified regs -> 12 waves/CU, LDS 3x48 KB
//      -> THREE independent wgs/CU whose barrier domains drift out of phase
//      -> cross-wg LDS<->MFMA overlap (m114 mechanism).
//      Keeps: both-sides XOR swizzle, counted VMW(4), setprio, XCD swizzle.
// ---------------------------------------------------------------------------

typedef __bf16 bf16;
typedef bf16 bf16x8 __attribute__((ext_vector_type(8)));
typedef bf16 bf16x4 __attribute__((ext_vector_type(4)));
typedef float f32x4 __attribute__((ext_vector_type(4)));

#define BB 4
#define SS 2048
#define CC 2048
#define DD 512
#define ND3 1536          // 3*DD
#define MM 8192           // BB*SS

typedef const __attribute__((address_space(1))) unsigned int g_u32;
typedef __attribute__((address_space(3))) unsigned int l_u32;

__device__ __forceinline__ void gl_lds16(const bf16* g, bf16* l) {
    __builtin_amdgcn_global_load_lds((g_u32*)g, (l_u32*)l, 16, 0, 0);
}

#define VMW(n) asm volatile("s_waitcnt vmcnt(" #n ")" ::: "memory")
#define BAR    __builtin_amdgcn_s_barrier()

// XCD-aware swizzle: dispatch slot d runs on XCD d%8; remap so XCD k gets a
// CONTIGUOUS work range. Requires nwg % 8 == 0 (all grids: 768/1024/256/1024).
__device__ __forceinline__ void xcd_swz(int& bx, int& by, int& bz) {
    const int gx = gridDim.x, gy = gridDim.y;
    const int nwg = gx * gy * gridDim.z;
    const int d = (blockIdx.z * gy + blockIdx.y) * gx + blockIdx.x;
    const int s = (d & 7) * (nwg >> 3) + (d >> 3);
    bx = s % gx;
    const int t2 = s / gx;
    by = t2 % gy;
    bz = t2 / gy;
}

// ---------------- prep: fp32->bf16 for x/Wqkv/Wo + zero rsum ---------------
#define N4_X   (MM * CC / 4)          // 4194304
#define N4_WQ  (ND3 * CC / 4)         //  786432
#define N4_WO  (CC * DD / 4)          //  262144
#define N4_RS  (MM / 4)               //    2048
#define N4_TOT (N4_X + N4_WQ + N4_WO + N4_RS)

__global__ __launch_bounds__(256) void prep(const float* __restrict__ x,
                                            const float* __restrict__ Wqkv,
                                            const float* __restrict__ Wo,
                                            bf16* __restrict__ xb,
                                            bf16* __restrict__ wqkvb,
                                            bf16* __restrict__ wob,
                                            float* __restrict__ rsum) {
    int i = blockIdx.x * 256 + threadIdx.x;
    const int stride = gridDim.x * 256;
    for (; i < N4_TOT; i += stride) {
        if (i < N4_X + N4_WQ + N4_WO) {
            const float* src; bf16* dst; int j = i;
            if (j < N4_X)                { src = x;    dst = xb; }
            else if (j < N4_X + N4_WQ)   { src = Wqkv; dst = wqkvb; j -= N4_X; }
            else                         { src = Wo;   dst = wob;   j -= N4_X + N4_WQ; }
            float4 v = ((const float4*)src)[j];
            bf16x4 o;
            o[0] = (bf16)v.x; o[1] = (bf16)v.y; o[2] = (bf16)v.z; o[3] = (bf16)v.w;
            ((bf16x4*)dst)[j] = o;
        } else {
            int j = i - (N4_X + N4_WQ + N4_WO);
            ((float4*)rsum)[j] = float4{0.f, 0.f, 0.f, 0.f};
        }
    }
}

// ---------------------------------------------------------------------------
// 128x128 ring core. 4 waves (2Mx2N), per-wave 64x64 output (acc[4][4]).
// K in 32-col chunks, 3-slot static-LDS ring: slot = A(128x32)+B(128x32)
// = 16 KB; 3 slots = 48 KB -> 3 wgs/CU (LDS 144 <= 160, regs ~150x12 <= 2048).
// Chunk j: 8 ds_read | STAGE(j+2) (4 gl_lds) | 16 MFMA | vmcnt(4) | barrier.
// VMW(4) leaves only STAGE(j+2) outstanding => chunk j+1 landed per-wave;
// barrier after the per-wave VMW makes it landed for ALL waves. Slot reuse:
// STAGE(j+2) writes slot (j+2)%3 whose reads (chunk j-1) finished before the
// previous barrier. Tail: VMW(0) before chunk NC-1.
// Swizzle: LDS linear (gl_lds req); global SOURCE granule = g ^ ((row>>1)&3);
// read applies the same XOR -> lane quad q reads global k-granule q.
// EPI: 0 = scale*acc + bias[col], row-major fp32 stores (k_out)
//      3 = QKV split: col<1024 row-major bf16; col>=1024 transposed into vT
//      4 = scoresT: exp(scale*acc), packed b64 C^T store, col-sum atomics
//      5 = pvT: acc/rowsum[col], packed b64 C^T store
// ---------------------------------------------------------------------------
#define SLOT3 8192        // bf16 elems per slot (A 4096 + B 4096)

template <bool OUT_BF16, int EPI>
__device__ __forceinline__ void gemm128_body(const bf16* __restrict__ A,
                                             const bf16* __restrict__ Bm,
                                             const float* __restrict__ bias,
                                             float* __restrict__ rowsum,
                                             bf16* __restrict__ vTp,
                                             void* __restrict__ Cv,
                                             int K, int lda, int ldb, int ldc,
                                             long ab, long bb, long cb,
                                             float scale) {
    __shared__ bf16 lds[3 * SLOT3];
    int bx, by, bz;
    xcd_swz(bx, by, bz);
    A  += (size_t)bz * ab;
    Bm += (size_t)bz * bb;
    const int m0 = by * 128, n0 = bx * 128;
    const int t = threadIdx.x, lane = t & 63, w = t >> 6;
    const int wm = (w >> 1) * 64, wn = (w & 1) * 64;
    const int cl = lane & 15, q = lane >> 4;
    const int swzr = (q ^ ((cl >> 1) & 3)) * 8;        // read-side XOR swizzle
    const int srow = t >> 2;                           // 0..63
    const int swz  = (t & 3) ^ ((t >> 3) & 3);
    const bf16* pa = A  + (size_t)(m0 + srow) * lda + swz * 8;
    const bf16* pb = Bm + (size_t)(n0 + srow) * ldb + swz * 8;
    bf16* lw = lds + w * 512;                          // wave-uniform base

    f32x4 acc[4][4] = {};
    const int NC = K >> 5;                             // K/32 chunks (>= 3)

    auto STAGE = [&](int j, int sl) {                  // slot sl = j % 3
        bf16* s = lw + sl * SLOT3;
        const bf16* ga = pa + j * 32;
        const bf16* gb = pb + j * 32;
        gl_lds16(ga,                    s);
        gl_lds16(ga + (size_t)64 * lda, s + 2048);
        gl_lds16(gb,                    s + 4096);
        gl_lds16(gb + (size_t)64 * ldb, s + 4096 + 2048);
    };
    auto FRAGS = [&](int sl, bf16x8 (&af)[4], bf16x8 (&bfr)[4]) {
        const bf16* sa = lds + sl * SLOT3 + (wm + cl) * 32 + swzr;
        const bf16* sb = lds + sl * SLOT3 + 4096 + (wn + cl) * 32 + swzr;
#pragma unroll
        for (int i = 0; i < 4; i++)  af[i]  = *(const bf16x8*)(sa + i * 512);
#pragma unroll
        for (int jj = 0; jj < 4; jj++) bfr[jj] = *(const bf16x8*)(sb + jj * 512);
    };
    auto MFMAS = [&](bf16x8 (&af)[4], bf16x8 (&bfr)[4]) {
        __builtin_amdgcn_s_setprio(1);
#pragma unroll
        for (int i = 0; i < 4; i++)
#pragma unroll
            for (int jj = 0; jj < 4; jj++)
                acc[i][jj] = __builtin_amdgcn_mfma_f32_16x16x32_bf16(
                                 af[i], bfr[jj], acc[i][jj], 0, 0, 0);
        __builtin_amdgcn_s_setprio(0);
    };

    STAGE(0, 0); STAGE(1, 1);
    VMW(4); BAR;                       // chunk 0 landed (all waves)

    int rd = 0, st = 2;                // read slot of chunk j; stage slot j+2
    for (int j = 0; j < NC - 2; ++j) {
        bf16x8 af[4], bfr[4];
        FRAGS(rd, af, bfr);
        STAGE(j + 2, st);
        MFMAS(af, bfr);
        VMW(4); BAR;                   // chunk j+1 landed everywhere
        rd = (rd == 2) ? 0 : rd + 1;
        st = (st == 2) ? 0 : st + 1;
    }
    {   bf16x8 af[4], bfr[4];
        FRAGS(rd, af, bfr); MFMAS(af, bfr);
        VMW(0); BAR;                   // chunk NC-1 landed
        rd = (rd == 2) ? 0 : rd + 1;
    }
    {   bf16x8 af[4], bfr[4];
        FRAGS(rd, af, bfr); MFMAS(af, bfr);
    }

    if constexpr (EPI == 4) {          // scoresT: exp, packed C^T, col-sums
        float cs[4] = {0.f, 0.f, 0.f, 0.f};
#pragma unroll
        for (int i = 0; i < 4; i++)
#pragma unroll
            for (int jj = 0; jj < 4; jj++) {
                int col = n0 + wn + jj * 16 + cl;
                int row = m0 + wm + i * 16 + q * 4;
                bf16x4 o;
#pragma unroll
                for (int r = 0; r < 4; r++) {
                    float e = __expf(acc[i][jj][r] * scale);
                    cs[jj] += e;
                    o[r] = (bf16)e;
                }
                *(bf16x4*)&((bf16*)Cv)[(size_t)bz * cb + (size_t)col * ldc + row] = o;
            }
#pragma unroll
        for (int jj = 0; jj < 4; jj++) {
            cs[jj] += __shfl_xor(cs[jj], 16, 64);
            cs[jj] += __shfl_xor(cs[jj], 32, 64);
        }
        if (q == 0) {
#pragma unroll
            for (int jj = 0; jj < 4; jj++)
                atomicAdd(&rowsum[(size_t)bz * SS + n0 + wn + jj * 16 + cl], cs[jj]);
        }
        return;
    }

    if constexpr (EPI == 5) {          // pvT: /rowsum[col=q], packed C^T
        float inv[4];
#pragma unroll
        for (int jj = 0; jj < 4; jj++)
            inv[jj] = 1.0f / rowsum[(size_t)bz * SS + n0 + wn + jj * 16 + cl];
#pragma unroll
        for (int i = 0; i < 4; i++)
#pragma unroll
            for (int jj = 0; jj < 4; jj++) {
                int col = n0 + wn + jj * 16 + cl;
                int row = m0 + wm + i * 16 + q * 4;
                bf16x4 o;
#pragma unroll
                for (int r = 0; r < 4; r++) o[r] = (bf16)(acc[i][jj][r] * inv[jj]);
                *(bf16x4*)&((bf16*)Cv)[(size_t)bz * cb + (size_t)col * ldc + row] = o;
            }
        return;
    }

    const bool v_block = (EPI == 3) && (n0 >= 1024);
#pragma unroll
    for (int i = 0; i < 4; i++) {
#pragma unroll
        for (int jj = 0; jj < 4; jj++) {
            int col = n0 + wn + jj * 16 + cl;
            float bvv = bias ? bias[col] : 0.0f;
            if (v_block) {
                int row = m0 + wm + i * 16 + q * 4;
                int b = row >> 11, s = row & 2047;
                bf16x4 o;
#pragma unroll
                for (int r = 0; r < 4; r++) o[r] = (bf16)(acc[i][jj][r] * scale + bvv);
                *(bf16x4*)&vTp[((size_t)b * DD + (col - 1024)) * SS + s] = o;
            } else {
#pragma unroll
                for (int r = 0; r < 4; r++) {
                    int row = m0 + wm + i * 16 + q * 4 + r;
                    float val = acc[i][jj][r] * scale + bvv;
                    if (OUT_BF16)
                        ((bf16*)Cv)[(size_t)bz * cb + (size_t)row * ldc + col] = (bf16)val;
                    else
                        ((float*)Cv)[(size_t)bz * cb + (size_t)row * ldc + col] = val;
                }
            }
        }
    }
}

// distinct names so rocprof reports per-role counters
__global__ __launch_bounds__(256, 2) void k_qkv(const bf16* A, const bf16* Bm,
        const float* bias, bf16* vTp, void* Cv, int K, int lda, int ldb, int ldc,
        float scale) {
    gemm128_body<true, 3>(A, Bm, bias, nullptr, vTp, Cv, K, lda, ldb, ldc, 0, 0, 0, scale);
}
__global__ __launch_bounds__(256, 2) void k_score(const bf16* A, const bf16* Bm,
        float* rowsum, void* Cv, int K, int lda, int ldb, int ldc,
        long ab, long bb, long cb, float scale) {
    gemm128_body<true, 4>(A, Bm, nullptr, rowsum, nullptr, Cv, K, lda, ldb, ldc, ab, bb, cb, scale);
}
__global__ __launch_bounds__(256, 2) void k_pv(const bf16* A, const bf16* Bm,
        float* rowsum, void* Cv, int K, int lda, int ldb, int ldc,
        long ab, long bb, long cb) {
    gemm128_body<true, 5>(A, Bm, nullptr, rowsum, nullptr, Cv, K, lda, ldb, ldc, ab, bb, cb, 1.0f);
}
__global__ __launch_bounds__(256, 2) void k_out(const bf16* A, const bf16* Bm,
        const float* bias, void* Cv, int K, int lda, int ldb, int ldc,
        float scale) {
    gemm128_body<false, 0>(A, Bm, bias, nullptr, nullptr, Cv, K, lda, ldb, ldc, 0, 0, 0, scale);
}

// ---------------------------------------------------------------------------
extern "C" void kernel_launch(void* const* d_in, const int* in_sizes, int n_in,
                              void* d_out, int out_size, void* d_ws, size_t ws_size,
                              hipStream_t stream) {
    const float* x    = (const float*)d_in[0];  // (4,2048,2048)
    const float* Wqkv = (const float*)d_in[1];  // (1536,2048)
    const float* bqkv = (const float*)d_in[2];  // (1536,)
    const float* Wo   = (const float*)d_in[3];  // (2048,512)
    const float* bo   = (const float*)d_in[4];  // (2048,)
    float* out = (float*)d_out;                 // (4,2048,2048) fp32

    char* ws = (char*)d_ws;
    size_t off = 0;
    bf16* xb    = (bf16*)(ws + off); off += (size_t)MM * CC * 2;       // 32 MB
    bf16* wqkvb = (bf16*)(ws + off); off += (size_t)ND3 * CC * 2;      // 6 MB
    bf16* wob   = (bf16*)(ws + off); off += (size_t)CC * DD * 2;       // 2 MB
    bf16* qkvb  = (bf16*)(ws + off); off += (size_t)MM * ND3 * 2;      // 24 MB
    bf16* vT    = (bf16*)(ws + off); off += (size_t)BB * DD * SS * 2;  // 8 MB
    bf16* expS  = (bf16*)(ws + off); off += (size_t)BB * SS * SS * 2;  // 32 MB
    bf16* ctxb  = (bf16*)(ws + off); off += (size_t)MM * DD * 2;       // 8 MB
    float* rsum = (float*)(ws + off); off += (size_t)MM * 4;           // 32 KB

    // 1. convert inputs to bf16 + zero rsum
    prep<<<2048, 256, 0, stream>>>(x, Wqkv, Wo, xb, wqkvb, wob, rsum);

    // 2. qkv = x Wqkv^T + bqkv; q,k -> qkvb rows, v -> vT transposed
    //    grid 12x64 = 768 wgs
    k_qkv<<<dim3(ND3 / 128, MM / 128, 1), 256, 0, stream>>>(
        xb, wqkvb, bqkv, vT, qkvb, CC, CC, CC, ND3, 1.0f);

    // 3. expS = exp(q k^T / sqrt(d)) via S^T = k q^T; packed C^T store gives
    //    expS[q][k] row-major; col-sum atomics -> rsum[q].  16x16x4 = 1024 wgs
    k_score<<<dim3(SS / 128, SS / 128, BB), 256, 0, stream>>>(
        qkvb + 512 /*k*/, qkvb /*q*/, rsum, expS,
        DD, ND3, ND3, SS,
        (long)SS * ND3, (long)SS * ND3, (long)SS * SS,
        0.044194173824159216f /* 1/sqrt(512) */);

    // 4. ctx[q][d] via ctx^T = vT expS^T; /rowsum[col]; packed C^T stores.
    //    grid 16x4x4 = 256 wgs
    k_pv<<<dim3(SS / 128, DD / 128, BB), 256, 0, stream>>>(
        vT, expS, rsum, ctxb,
        SS, SS, SS, DD,
        (long)DD * SS, (long)SS * SS, (long)SS * DD);

    // 5. out = ctx Wo^T + bo  (M=8192, N=2048, K=512) -> fp32.  16x64 = 1024
    k_out<<<dim3(CC / 128, MM / 128, 1), 256, 0, stream>>>(
        ctxb, wob, bo, out, DD, DD, DD, CC, 1.0f);

    (void)in_sizes; (void)n_in; (void)out_size; (void)ws_size;
}